// Round 7
// baseline (374.881 us; speedup 1.0000x reference)
//
#include <hip/hip_runtime.h>
#include <hip/hip_bf16.h>
#include <stdint.h>

// VectorQuantizer on MI355X.
//   z: (8,256,32,32) f32  -> rows = 8192, K = 256
//   embed_w: (16384,256) f32
// out: z_q (2097152 f32) + loss (1 f32)
// k_prep: z->bf16 blocked; ew->bf16 blocked + (-0.5||e||^2) + loss=0
// k_main: fused GEMM+argmax, ring-4 LDS, counted-vmcnt deep pipeline (T3/T4)
// k_fin : reduce 16 partials -> full-row 1KB gathers -> LDS transpose -> out+loss

typedef __attribute__((ext_vector_type(8))) short bf16x8;
typedef __attribute__((ext_vector_type(8))) unsigned short ushort8v;
typedef __attribute__((ext_vector_type(4))) float f32x4;

__device__ __forceinline__ unsigned short f2bf(float f) {
  unsigned u = __float_as_uint(f);
  return (unsigned short)((u + 0x7FFFu + ((u >> 16) & 1u)) >> 16);
}

typedef const __attribute__((address_space(1))) unsigned char* gas1;
typedef __attribute__((address_space(3))) unsigned char* las3;
__device__ __forceinline__ void cp16g(const void* g, void* l) {
  __builtin_amdgcn_global_load_lds((gas1)g, (las3)l, 16, 0, 0);
}

// ---------------- P: fused prep ------------------------------------------------
__global__ void k_prep(const float* __restrict__ z, const float* __restrict__ ew,
                       unsigned short* __restrict__ zp, unsigned short* __restrict__ ep,
                       float* __restrict__ h2, float* __restrict__ out) {
  __shared__ float tile[32][132];
  int bid = blockIdx.x;
  int t = threadIdx.x;
  if (bid < 512) {
    int b = bid >> 6, ct = (bid >> 3) & 7, hwt = bid & 7;
    const float* src = z + b * 262144 + ct * 32768 + hwt * 128;
#pragma unroll
    for (int it = 0; it < 4; ++it) {
      int cell = it * 1024 + t * 4;
      int cl = cell >> 7, hl = cell & 127;
      float4 v = *(const float4*)(src + cl * 1024 + hl);
      *(float4*)(&tile[cl][hl]) = v;
    }
    __syncthreads();
    int mt = b * 8 + hwt;
    unsigned short* dst = zp + mt * 32768 + ct * 4096;  // ct == kstep
#pragma unroll
    for (int it = 0; it < 2; ++it) {
      int cell = it * 256 + t;
      int kg = cell >> 7, r = cell & 127;
      ushort8v v;
#pragma unroll
      for (int j = 0; j < 8; ++j) v[j] = f2bf(tile[kg * 8 + j][r]);
      *(ushort8v*)(dst + cell * 8) = v;
    }
  } else {
    if (bid == 512 && t == 0) out[2097152] = 0.0f;
    int n = (bid - 512) * 32 + (t >> 3);
    int nb = n >> 7, col = n & 127;
    float s = 0.0f;
#pragma unroll
    for (int it = 0; it < 4; ++it) {
      int cellk = (t & 7) + it * 8;
      const float4 x = *(const float4*)(ew + n * 256 + cellk * 8);
      const float4 y = *(const float4*)(ew + n * 256 + cellk * 8 + 4);
      s += x.x * x.x + x.y * x.y + x.z * x.z + x.w * x.w
         + y.x * y.x + y.y * y.y + y.z * y.z + y.w * y.w;
      int ks = cellk >> 2, kg = cellk & 3;
      ushort8v v;
      v[0] = f2bf(x.x); v[1] = f2bf(x.y); v[2] = f2bf(x.z); v[3] = f2bf(x.w);
      v[4] = f2bf(y.x); v[5] = f2bf(y.y); v[6] = f2bf(y.z); v[7] = f2bf(y.w);
      *(ushort8v*)(ep + nb * 32768 + ks * 4096 + kg * 1024 + col * 8) = v;
    }
#pragma unroll
    for (int off = 1; off <= 4; off <<= 1) s += __shfl_xor(s, off);
    if ((t & 7) == 0) h2[n] = -0.5f * s;   // NEGATED: k_main acc init is a mov
  }
}

// ---------------- Main: fused GEMM + argmax, counted-vmcnt pipeline ------------
// grid (16 seg, 64 mt), 256 thr. 32 steps; step s: cols [nb*128,+128), k [ph*64,+64).
// Ring-4 B buffers (16 KB each), prefetch depth 3, vmcnt(12) steady state.
// In-loop VMEM is ONLY cp16 staging (4/wave/step) -> waitcnt ledger is exact.
__global__ __launch_bounds__(256, 2) void k_main(
    const unsigned short* __restrict__ zp, const unsigned short* __restrict__ ep,
    const float* __restrict__ h2, int2* __restrict__ partial) {
  __shared__ unsigned char lds[4 * 16384 + 4096];
  unsigned char* ldsring = lds;
  const float* hLds = (const float*)(lds + 65536);
  int seg = blockIdx.x;   // 0..15; dispatch id%8 == seg%8 -> XCD-affine B panels
  int mt = blockIdx.y;    // 0..63
  int t = threadIdx.x, wv = t >> 6, lane = t & 63;
  int l15 = lane & 15, kg = lane >> 4;

  // A tile -> registers: av[m*8+ks], 16B fragments
  bf16x8 av[16];
  const unsigned short* abase = zp + mt * 32768;
#pragma unroll
  for (int m = 0; m < 2; ++m)
#pragma unroll
    for (int ks = 0; ks < 8; ++ks)
      av[m * 8 + ks] = *(const bf16x8*)(abase + ks * 4096 + kg * 1024 +
                                        (wv * 32 + m * 16 + l15) * 8);

  const unsigned char* bsrc = (const unsigned char*)ep + seg * 524288;
  const unsigned char* bstage = bsrc + wv * 1024 + lane * 16;  // per-lane src
  int ldsw = wv * 1024;                                        // wave-uniform dest

  // prologue: h2 segment (4 KB) + stages 0..2 (counted: 1 + 12 cp16/wave)
  cp16g((const unsigned char*)(h2 + seg * 1024) + wv * 1024 + lane * 16,
        lds + 65536 + ldsw);
#pragma unroll
  for (int s0 = 0; s0 < 3; ++s0) {
    const unsigned char* sg = bstage + s0 * 16384;
    unsigned char* sd = ldsring + s0 * 16384 + ldsw;
#pragma unroll
    for (int i = 0; i < 4; ++i) cp16g(sg + i * 4096, sd + i * 4096);
  }

  f32x4 acc[2][8];
  float best[2][4];
#pragma unroll
  for (int m = 0; m < 2; ++m)
#pragma unroll
    for (int r = 0; r < 4; ++r) best[m][r] = -3.4e38f;

#define STEP(S, VM)                                                              \
  {                                                                              \
    if ((S) < 29) {                                                              \
      const unsigned char* sg = bstage + ((S) + 3) * 16384;                      \
      unsigned char* sd = ldsring + (((S) + 3) & 3) * 16384 + ldsw;              \
      cp16g(sg, sd);                                                             \
      cp16g(sg + 4096, sd + 4096);                                               \
      cp16g(sg + 8192, sd + 8192);                                               \
      cp16g(sg + 12288, sd + 12288);                                             \
    }                                                                            \
    asm volatile("s_waitcnt vmcnt(" VM ")" ::: "memory");                        \
    asm volatile("s_barrier" ::: "memory");                                      \
    {                                                                            \
      const int nb = (S) >> 2, ph = (S) & 3;                                     \
      if (ph == 0) {                                                             \
        _Pragma("unroll") for (int nf = 0; nf < 8; ++nf) {                       \
          float h = hLds[nb * 128 + nf * 16 + l15];                              \
          acc[0][nf] = (f32x4){h, h, h, h};                                      \
          acc[1][nf] = acc[0][nf];                                               \
        }                                                                        \
      }                                                                          \
      const unsigned char* bp = ldsring + ((S) & 3) * 16384 + kg * 2048 + l15 * 16; \
      __builtin_amdgcn_s_setprio(1);                                             \
      _Pragma("unroll") for (int k2 = 0; k2 < 2; ++k2) {                         \
        bf16x8 bv[8];                                                            \
        _Pragma("unroll") for (int nf = 0; nf < 8; ++nf)                         \
          bv[nf] = *(const bf16x8*)(bp + k2 * 8192 + nf * 256);                  \
        _Pragma("unroll") for (int m = 0; m < 2; ++m)                            \
          _Pragma("unroll") for (int nf = 0; nf < 8; ++nf)                       \
            acc[m][nf] = __builtin_amdgcn_mfma_f32_16x16x32_bf16(                \
                av[m * 8 + ph * 2 + k2], bv[nf], acc[m][nf], 0, 0, 0);           \
      }                                                                          \
      __builtin_amdgcn_s_setprio(0);                                             \
      asm volatile("s_barrier" ::: "memory");                                    \
      if (ph == 3) {                                                             \
        unsigned colbase = (unsigned)(nb * 128 + l15);                           \
        _Pragma("unroll") for (int m = 0; m < 2; ++m)                            \
          _Pragma("unroll") for (int nf = 0; nf < 8; ++nf) {                     \
            unsigned lcol = colbase + nf * 16u;                                  \
            _Pragma("unroll") for (int r = 0; r < 4; ++r) {                      \
              unsigned p = (__float_as_uint(acc[m][nf][r]) & 0xFFFFF800u) | lcol;\
              best[m][r] = fmaxf(best[m][r], __uint_as_float(p));                \
            }                                                                    \
          }                                                                      \
      }                                                                          \
    }                                                                            \
  }

  STEP(0, "12")  STEP(1, "12")  STEP(2, "12")  STEP(3, "12")
  STEP(4, "12")  STEP(5, "12")  STEP(6, "12")  STEP(7, "12")
  STEP(8, "12")  STEP(9, "12")  STEP(10, "12") STEP(11, "12")
  STEP(12, "12") STEP(13, "12") STEP(14, "12") STEP(15, "12")
  STEP(16, "12") STEP(17, "12") STEP(18, "12") STEP(19, "12")
  STEP(20, "12") STEP(21, "12") STEP(22, "12") STEP(23, "12")
  STEP(24, "12") STEP(25, "12") STEP(26, "12") STEP(27, "12")
  STEP(28, "12") STEP(29, "8")  STEP(30, "4")  STEP(31, "0")
#undef STEP

  // cross-lane (16 cols/group) argmax reduce, write per-(row,segment) partial
#pragma unroll
  for (int m = 0; m < 2; ++m)
#pragma unroll
    for (int r = 0; r < 4; ++r) {
      float bvv = best[m][r];
#pragma unroll
      for (int off = 1; off <= 8; off <<= 1) bvv = fmaxf(bvv, __shfl_xor(bvv, off));
      if (l15 == 0) {
        unsigned bits = __float_as_uint(bvv);
        int gidx = seg * 1024 + (int)(bits & 0x7FFu);
        int row = mt * 128 + wv * 32 + m * 16 + kg * 4 + r;
        partial[seg * 8192 + row] = make_int2((int)bits, gidx);
      }
    }
}

// -------- Final: reduce partials -> full-row gather -> transpose -> out+loss ---
// 256 blocks = (b 0..7, pxt 0..31); 32 pixels x 256 ch each.
// Gather: one wave reads one 1KB code row fully coalesced (64 lanes x 16B).
__global__ void k_fin(const int2* __restrict__ partial, const float* __restrict__ ew,
                      const float* __restrict__ z, float* __restrict__ out) {
  __shared__ float tile[32][260];   // [px][ch], padded
  __shared__ int codeIdx[32];
  int bid = blockIdx.x;
  int b = bid >> 5, pxt = bid & 31;
  int t = threadIdx.x, wv = t >> 6, lane = t & 63;
  if (t < 32) {
    int row = b * 1024 + pxt * 32 + t;
    float bb = -3.4e38f;
    int bi = 0;
#pragma unroll
    for (int s = 0; s < 16; ++s) {
      int2 p = partial[s * 8192 + row];
      float v = __int_as_float(p.x);
      if (v > bb) { bb = v; bi = p.y; }
    }
    codeIdx[t] = bi;
  }
  __syncthreads();
#pragma unroll
  for (int i = 0; i < 8; ++i) {
    int px = wv * 8 + i;
    int idx = codeIdx[px];
    float4 v = *(const float4*)(ew + idx * 256 + lane * 4);
    *(float4*)(&tile[px][lane * 4]) = v;
  }
  __syncthreads();
  float ls = 0.0f;
  int zbase = b * 262144 + pxt * 32;
#pragma unroll
  for (int j = 0; j < 8; ++j) {
    int c = wv * 64 + j * 8 + (lane >> 3);
    int p4 = (lane & 7) * 4;
    float4 q;
    q.x = tile[p4][c]; q.y = tile[p4 + 1][c]; q.z = tile[p4 + 2][c]; q.w = tile[p4 + 3][c];
    const float* zp_ = z + zbase + c * 1024 + p4;
    float4 zv = *(const float4*)zp_;
    float dx = q.x - zv.x, dy = q.y - zv.y, dz = q.z - zv.z, dw = q.w - zv.w;
    ls += dx * dx + dy * dy + dz * dz + dw * dw;
    *(float4*)(out + zbase + c * 1024 + p4) = q;
  }
#pragma unroll
  for (int off = 32; off; off >>= 1) ls += __shfl_xor(ls, off);
  if (lane == 0) atomicAdd(out + 2097152, ls * (2.0f / 2097152.0f));
}

extern "C" void kernel_launch(void* const* d_in, const int* in_sizes, int n_in,
                              void* d_out, int out_size, void* d_ws, size_t ws_size,
                              hipStream_t stream) {
  const float* z = (const float*)d_in[0];
  const float* ew = (const float*)d_in[1];
  float* out = (float*)d_out;
  unsigned char* ws = (unsigned char*)d_ws;
  unsigned short* zp = (unsigned short*)ws;                           // 4 MB
  unsigned short* ep = (unsigned short*)(ws + (4u << 20));            // 8 MB
  float* h2 = (float*)(ws + (12u << 20));                             // 64 KB
  int2* partial = (int2*)(ws + (12u << 20) + 65536);                  // 1 MB

  k_prep<<<1024, 256, 0, stream>>>(z, ew, zp, ep, h2, out);
  k_main<<<dim3(16, 64), 256, 0, stream>>>(zp, ep, h2, partial);
  k_fin<<<256, 256, 0, stream>>>(partial, ew, z, out);
}

// Round 11
// 152.282 us; speedup vs baseline: 2.4618x; 2.4618x over previous
//
#include <hip/hip_runtime.h>
#include <hip/hip_bf16.h>
#include <stdint.h>

// VectorQuantizer on MI355X.
//   z: (8,256,32,32) f32  -> rows = 8192, K = 256
//   embed_w: (16384,256) f32
// out: z_q (2097152 f32) + loss (1 f32)
// k_prep: z->bf16 blocked; ew->bf16 blocked + (-0.5||e||^2) + loss=0
// k_main: fused GEMM+argmax, ring-4 LDS, counted vmcnt(4), rolled nb loop
// k_fin : reduce 16 partials -> full-row 1KB gathers -> LDS transpose -> out+loss

typedef __attribute__((ext_vector_type(8))) short bf16x8;
typedef __attribute__((ext_vector_type(8))) unsigned short ushort8v;
typedef __attribute__((ext_vector_type(4))) float f32x4;

__device__ __forceinline__ unsigned short f2bf(float f) {
  unsigned u = __float_as_uint(f);
  return (unsigned short)((u + 0x7FFFu + ((u >> 16) & 1u)) >> 16);
}

typedef const __attribute__((address_space(1))) unsigned char* gas1;
typedef __attribute__((address_space(3))) unsigned char* las3;
__device__ __forceinline__ void cp16g(const void* g, void* l) {
  __builtin_amdgcn_global_load_lds((gas1)g, (las3)l, 16, 0, 0);
}

// ---------------- P: fused prep ------------------------------------------------
__global__ void k_prep(const float* __restrict__ z, const float* __restrict__ ew,
                       unsigned short* __restrict__ zp, unsigned short* __restrict__ ep,
                       float* __restrict__ h2, float* __restrict__ out) {
  __shared__ float tile[32][132];
  int bid = blockIdx.x;
  int t = threadIdx.x;
  if (bid < 512) {
    int b = bid >> 6, ct = (bid >> 3) & 7, hwt = bid & 7;
    const float* src = z + b * 262144 + ct * 32768 + hwt * 128;
#pragma unroll
    for (int it = 0; it < 4; ++it) {
      int cell = it * 1024 + t * 4;
      int cl = cell >> 7, hl = cell & 127;
      float4 v = *(const float4*)(src + cl * 1024 + hl);
      *(float4*)(&tile[cl][hl]) = v;
    }
    __syncthreads();
    int mt = b * 8 + hwt;
    unsigned short* dst = zp + mt * 32768 + ct * 4096;  // ct == kstep
#pragma unroll
    for (int it = 0; it < 2; ++it) {
      int cell = it * 256 + t;
      int kg = cell >> 7, r = cell & 127;
      ushort8v v;
#pragma unroll
      for (int j = 0; j < 8; ++j) v[j] = f2bf(tile[kg * 8 + j][r]);
      *(ushort8v*)(dst + cell * 8) = v;
    }
  } else {
    if (bid == 512 && t == 0) out[2097152] = 0.0f;
    int n = (bid - 512) * 32 + (t >> 3);
    int nb = n >> 7, col = n & 127;
    float s = 0.0f;
#pragma unroll
    for (int it = 0; it < 4; ++it) {
      int cellk = (t & 7) + it * 8;
      const float4 x = *(const float4*)(ew + n * 256 + cellk * 8);
      const float4 y = *(const float4*)(ew + n * 256 + cellk * 8 + 4);
      s += x.x * x.x + x.y * x.y + x.z * x.z + x.w * x.w
         + y.x * y.x + y.y * y.y + y.z * y.z + y.w * y.w;
      int ks = cellk >> 2, kg = cellk & 3;
      ushort8v v;
      v[0] = f2bf(x.x); v[1] = f2bf(x.y); v[2] = f2bf(x.z); v[3] = f2bf(x.w);
      v[4] = f2bf(y.x); v[5] = f2bf(y.y); v[6] = f2bf(y.z); v[7] = f2bf(y.w);
      *(ushort8v*)(ep + nb * 32768 + ks * 4096 + kg * 1024 + col * 8) = v;
    }
#pragma unroll
    for (int off = 1; off <= 4; off <<= 1) s += __shfl_xor(s, off);
    if ((t & 7) == 0) h2[n] = -0.5f * s;   // NEGATED: k_main acc init is a mov
  }
}

// ---------------- Main: fused GEMM + argmax ------------------------------------
// grid (16 seg, 64 mt), 256 thr. 32 steps; step s = nb*4+ph: cols [nb*128,+128),
// k [ph*64,+64). Ring-4 B buffers (16 KB), prefetch depth 2, vmcnt(4) steady.
// In-loop VMEM is ONLY cp16 staging (4/wave/step): ledger exact, per-wave
// vmcnt + barrier => global completion (waves stage symmetric slices).
// Buffer ph is compile-time constant (inner 4x unroll); outer nb loop ROLLED
// so stage-address live ranges stay short (the R6 full-unroll spilled).
__global__ __launch_bounds__(256, 2) void k_main(
    const unsigned short* __restrict__ zp, const unsigned short* __restrict__ ep,
    const float* __restrict__ h2, int2* __restrict__ partial) {
  __shared__ unsigned char ring[4][16384];
  __shared__ float hbuf[1024];
  int seg = blockIdx.x;   // 0..15
  int mt = blockIdx.y;    // 0..63
  int t = threadIdx.x, wv = t >> 6, lane = t & 63;
  int l15 = lane & 15, kg = lane >> 4;

  // A tile -> registers: av[m*8+ks], 16B fragments
  bf16x8 av[16];
  const unsigned short* abase = zp + mt * 32768;
#pragma unroll
  for (int m = 0; m < 2; ++m)
#pragma unroll
    for (int ks = 0; ks < 8; ++ks)
      av[m * 8 + ks] = *(const bf16x8*)(abase + ks * 4096 + kg * 1024 +
                                        (wv * 32 + m * 16 + l15) * 8);

  const unsigned char* bsrc = (const unsigned char*)ep + seg * 524288;
  const unsigned char* bstage = bsrc + wv * 1024 + lane * 16;  // per-lane src
  int ldsw = wv * 1024;                                        // wave-uniform dest

  // prologue: h2 (1 cp16/lane) + stage(0) (4) ... then stage(1) (4)
  cp16g((const unsigned char*)(h2 + seg * 1024) + ldsw + lane * 16,
        (unsigned char*)hbuf + ldsw);
#pragma unroll
  for (int i = 0; i < 4; ++i)
    cp16g(bstage + i * 4096, &ring[0][i * 4096 + ldsw]);
  __builtin_amdgcn_sched_barrier(0);   // pin: {h, stage0} strictly before stage1
#pragma unroll
  for (int i = 0; i < 4; ++i)
    cp16g(bstage + 16384 + i * 4096, &ring[1][i * 4096 + ldsw]);

  f32x4 acc[2][8];
  float best[2][4];
#pragma unroll
  for (int m = 0; m < 2; ++m)
#pragma unroll
    for (int r = 0; r < 4; ++r) best[m][r] = -3.4e38f;

#define KSTEP(PH, NB, DOSTAGE, VM)                                              \
  {                                                                             \
    asm volatile("s_waitcnt vmcnt(" VM ")" ::: "memory");                       \
    __builtin_amdgcn_s_barrier();                                               \
    if (DOSTAGE) {                                                              \
      const unsigned char* sg = bstage + ((NB) * 4 + (PH) + 2) * 16384;         \
      _Pragma("unroll") for (int i = 0; i < 4; ++i)                             \
        cp16g(sg + i * 4096, &ring[((PH) + 2) & 3][i * 4096 + ldsw]);           \
    }                                                                           \
    if ((PH) == 0) {                                                            \
      _Pragma("unroll") for (int nf = 0; nf < 8; ++nf) {                        \
        float h = hbuf[(NB) * 128 + nf * 16 + l15];                             \
        acc[0][nf] = (f32x4){h, h, h, h};                                       \
        acc[1][nf] = acc[0][nf];                                                \
      }                                                                         \
    }                                                                           \
    __builtin_amdgcn_s_setprio(1);                                              \
    _Pragma("unroll") for (int k2 = 0; k2 < 2; ++k2) {                          \
      bf16x8 bv[8];                                                             \
      _Pragma("unroll") for (int nf = 0; nf < 8; ++nf)                          \
        bv[nf] = *(const bf16x8*)(&ring[(PH)][k2 * 8192 + kg * 2048 +           \
                                             (nf * 16 + l15) * 16]);            \
      _Pragma("unroll") for (int m = 0; m < 2; ++m)                             \
        _Pragma("unroll") for (int nf = 0; nf < 8; ++nf)                        \
          acc[m][nf] = __builtin_amdgcn_mfma_f32_16x16x32_bf16(                 \
              av[m * 8 + (PH) * 2 + k2], bv[nf], acc[m][nf], 0, 0, 0);          \
    }                                                                           \
    __builtin_amdgcn_s_setprio(0);                                              \
    if ((PH) == 3) {                                                            \
      unsigned colbase = (unsigned)((NB) * 128 + l15);                          \
      _Pragma("unroll") for (int m = 0; m < 2; ++m)                             \
        _Pragma("unroll") for (int nf = 0; nf < 8; ++nf) {                      \
          unsigned lcol = colbase + nf * 16u;                                   \
          _Pragma("unroll") for (int r = 0; r < 4; ++r) {                       \
            unsigned p = (__float_as_uint(acc[m][nf][r]) & 0xFFFFF800u) | lcol; \
            best[m][r] = fmaxf(best[m][r], __uint_as_float(p));                 \
          }                                                                     \
        }                                                                       \
    }                                                                           \
  }

#pragma unroll 1
  for (int nb = 0; nb < 7; ++nb) {
    KSTEP(0, nb, 1, "4")
    KSTEP(1, nb, 1, "4")
    KSTEP(2, nb, 1, "4")
    KSTEP(3, nb, 1, "4")
  }
  KSTEP(0, 7, 1, "4")   // stages step 30
  KSTEP(1, 7, 1, "4")   // stages step 31 (last)
  KSTEP(2, 7, 0, "4")
  KSTEP(3, 7, 0, "0")
#undef KSTEP

  // cross-lane (16 cols/group) argmax reduce, write per-(row,segment) partial
#pragma unroll
  for (int m = 0; m < 2; ++m)
#pragma unroll
    for (int r = 0; r < 4; ++r) {
      float bvv = best[m][r];
#pragma unroll
      for (int off = 1; off <= 8; off <<= 1) bvv = fmaxf(bvv, __shfl_xor(bvv, off));
      if (l15 == 0) {
        unsigned bits = __float_as_uint(bvv);
        int gidx = seg * 1024 + (int)(bits & 0x7FFu);
        int row = mt * 128 + wv * 32 + m * 16 + kg * 4 + r;
        partial[seg * 8192 + row] = make_int2((int)bits, gidx);
      }
    }
}

// -------- Final: reduce partials -> full-row gather -> transpose -> out+loss ---
// 256 blocks = (b 0..7, pxt 0..31); 32 pixels x 256 ch each.
// Gather: one wave reads one 1KB code row fully coalesced (64 lanes x 16B).
__global__ void k_fin(const int2* __restrict__ partial, const float* __restrict__ ew,
                      const float* __restrict__ z, float* __restrict__ out) {
  __shared__ float tile[32][260];   // [px][ch], padded
  __shared__ int codeIdx[32];
  int bid = blockIdx.x;
  int b = bid >> 5, pxt = bid & 31;
  int t = threadIdx.x, wv = t >> 6, lane = t & 63;
  if (t < 32) {
    int row = b * 1024 + pxt * 32 + t;
    float bb = -3.4e38f;
    int bi = 0;
#pragma unroll
    for (int s = 0; s < 16; ++s) {
      int2 p = partial[s * 8192 + row];
      float v = __int_as_float(p.x);
      if (v > bb) { bb = v; bi = p.y; }
    }
    codeIdx[t] = bi;
  }
  __syncthreads();
#pragma unroll
  for (int i = 0; i < 8; ++i) {
    int px = wv * 8 + i;
    int idx = codeIdx[px];
    float4 v = *(const float4*)(ew + idx * 256 + lane * 4);
    *(float4*)(&tile[px][lane * 4]) = v;
  }
  __syncthreads();
  float ls = 0.0f;
  int zbase = b * 262144 + pxt * 32;
#pragma unroll
  for (int j = 0; j < 8; ++j) {
    int c = wv * 64 + j * 8 + (lane >> 3);
    int p4 = (lane & 7) * 4;
    float4 q;
    q.x = tile[p4][c]; q.y = tile[p4 + 1][c]; q.z = tile[p4 + 2][c]; q.w = tile[p4 + 3][c];
    const float* zp_ = z + zbase + c * 1024 + p4;
    float4 zv = *(const float4*)zp_;
    float dx = q.x - zv.x, dy = q.y - zv.y, dz = q.z - zv.z, dw = q.w - zv.w;
    ls += dx * dx + dy * dy + dz * dz + dw * dw;
    *(float4*)(out + zbase + c * 1024 + p4) = q;
  }
#pragma unroll
  for (int off = 32; off; off >>= 1) ls += __shfl_xor(ls, off);
  if (lane == 0) atomicAdd(out + 2097152, ls * (2.0f / 2097152.0f));
}

extern "C" void kernel_launch(void* const* d_in, const int* in_sizes, int n_in,
                              void* d_out, int out_size, void* d_ws, size_t ws_size,
                              hipStream_t stream) {
  const float* z = (const float*)d_in[0];
  const float* ew = (const float*)d_in[1];
  float* out = (float*)d_out;
  unsigned char* ws = (unsigned char*)d_ws;
  unsigned short* zp = (unsigned short*)ws;                           // 4 MB
  unsigned short* ep = (unsigned short*)(ws + (4u << 20));            // 8 MB
  float* h2 = (float*)(ws + (12u << 20));                             // 64 KB
  int2* partial = (int2*)(ws + (12u << 20) + 65536);                  // 1 MB

  k_prep<<<1024, 256, 0, stream>>>(z, ew, zp, ep, h2, out);
  k_main<<<dim3(16, 64), 256, 0, stream>>>(zp, ep, h2, partial);
  k_fin<<<256, 256, 0, stream>>>(partial, ew, z, out);
}